// Round 1
// baseline (159.845 us; speedup 1.0000x reference)
//
#include <hip/hip_runtime.h>
#include <math.h>

#define NHW 676               // 26*26
#define NB 256
#define NCELLS (NB * NHW)     // 173056
#define NC 20                 // classes
#define NA 5                  // anchors

__device__ __forceinline__ float sigmoidf_(float x) {
    return 1.0f / (1.0f + __expf(-x));
}

__global__ __launch_bounds__(256) void yolo_loss_kernel(
    const float* __restrict__ pred,   // (B, 125, 26, 26)
    const float* __restrict__ tgt,    // (B, 26, 26, 25)
    float* __restrict__ out)          // 4 floats: box, conf, noobj, cls
{
    const float AW[NA] = {1.3221f, 3.19275f, 5.05587f, 9.47112f, 11.2364f};
    const float AH[NA] = {1.73145f, 4.00944f, 8.09892f, 4.84053f, 10.0071f};

    int t = blockIdx.x * blockDim.x + threadIdx.x;

    float box_l = 0.0f, conf_l = 0.0f, noobj_l = 0.0f, cls_l = 0.0f;

    if (t < NCELLS) {
        int b  = t / NHW;
        int hw = t - b * NHW;
        const float* p  = pred + (size_t)b * 125 * NHW + hw;  // channel stride NHW
        const float* tg = tgt + (size_t)t * 25;

        float gconf = tg[20];
        float gx = tg[21], gy = tg[22], gw = tg[23], gh = tg[24];

        float g_x1 = gx - gw * 0.5f, g_x2 = gx + gw * 0.5f;
        float g_y1 = gy - gh * 0.5f, g_y2 = gy + gh * 0.5f;
        float g_area = gw * gh;

        float best_iou = -1.0f;
        int   best_a = 0;
        float bx = 0, by = 0, bw = 0, bh = 0, bconf = 0;

        #pragma unroll
        for (int a = 0; a < NA; ++a) {
            const float* pa = p + a * 25 * NHW;
            float tc = pa[20 * NHW];
            float tx = pa[21 * NHW];
            float ty = pa[22 * NHW];
            float tw = pa[23 * NHW];
            float th = pa[24 * NHW];
            float px = sigmoidf_(tx), py = sigmoidf_(ty);
            float pw = __expf(tw) * AW[a];
            float ph = __expf(th) * AH[a];
            float iw = fminf(px + pw * 0.5f, g_x2) - fmaxf(px - pw * 0.5f, g_x1);
            float ih = fminf(py + ph * 0.5f, g_y2) - fmaxf(py - ph * 0.5f, g_y1);
            iw = fmaxf(iw, 0.0f);
            ih = fmaxf(ih, 0.0f);
            float inter = iw * ih;
            float uni = pw * ph + g_area - inter;
            float iou = inter / (uni + 1e-10f);
            if (iou > best_iou) {   // strict > : first max wins ties, matches jnp.argmax
                best_iou = iou;
                best_a = a;
                bx = px; by = py; bw = pw; bh = ph;
                bconf = sigmoidf_(tc);
            }
        }

        bool obj = (gconf != 0.0f);
        if (obj) {
            float dx = bx - gx, dy = by - gy, dw = bw - gw, dh = bh - gh;
            box_l = dx * dx + dy * dy + dw * dw + dh * dh;
            float dc = bconf - gconf;
            conf_l = dc * dc;

            // class NLL for best anchor — only ~3% of cells reach here
            const float* pc = p + best_a * 25 * NHW;
            float m = -1e30f;
            float l_sel = 0.0f;
            #pragma unroll
            for (int k = 0; k < NC; ++k) {
                float l = pc[k * NHW];
                m = fmaxf(m, l);
                if (tg[k] > 0.5f) l_sel = l;   // one-hot target
            }
            float s = 0.0f;
            #pragma unroll
            for (int k = 0; k < NC; ++k) {
                s += __expf(pc[k * NHW] - m);  // re-load: L1-hot
            }
            cls_l = -(l_sel - m - __logf(s));
        } else {
            noobj_l = bconf * bconf;
        }
    }

    // wave (64-lane) reduction
    #pragma unroll
    for (int off = 32; off > 0; off >>= 1) {
        box_l   += __shfl_down(box_l,   off, 64);
        conf_l  += __shfl_down(conf_l,  off, 64);
        noobj_l += __shfl_down(noobj_l, off, 64);
        cls_l   += __shfl_down(cls_l,   off, 64);
    }

    __shared__ float sred[4][4];   // 4 waves x 4 partials
    int wave = threadIdx.x >> 6;
    int lane = threadIdx.x & 63;
    if (lane == 0) {
        sred[wave][0] = box_l;
        sred[wave][1] = conf_l;
        sred[wave][2] = noobj_l;
        sred[wave][3] = cls_l;
    }
    __syncthreads();
    if (threadIdx.x == 0) {
        float b0 = 0, b1 = 0, b2 = 0, b3 = 0;
        #pragma unroll
        for (int w = 0; w < 4; ++w) {
            b0 += sred[w][0];
            b1 += sred[w][1];
            b2 += sred[w][2];
            b3 += sred[w][3];
        }
        atomicAdd(&out[0], b0 * (5.0f / 256.0f));
        atomicAdd(&out[1], b1 * (1.0f / 256.0f));
        atomicAdd(&out[2], b2 * (0.5f / 256.0f));
        atomicAdd(&out[3], b3 * (1.0f / 256.0f));
    }
}

extern "C" void kernel_launch(void* const* d_in, const int* in_sizes, int n_in,
                              void* d_out, int out_size, void* d_ws, size_t ws_size,
                              hipStream_t stream) {
    const float* pred = (const float*)d_in[0];
    const float* tgt  = (const float*)d_in[1];
    float* out = (float*)d_out;

    hipMemsetAsync(out, 0, out_size * sizeof(float), stream);

    dim3 grid((NCELLS + 255) / 256);
    dim3 block(256);
    hipLaunchKernelGGL(yolo_loss_kernel, grid, block, 0, stream,
                       pred, tgt, out);
}

// Round 2
// 156.947 us; speedup vs baseline: 1.0185x; 1.0185x over previous
//
#include <hip/hip_runtime.h>
#include <math.h>

#define NHW 676               // 26*26
#define NB 256
#define NCELLS (NB * NHW)     // 173056 = 676 blocks * 256 threads exactly
#define NC 20                 // classes
#define NA 5                  // anchors

__device__ __forceinline__ float sigmoidf_(float x) {
    return 1.0f / (1.0f + __expf(-x));
}

__global__ __launch_bounds__(256) void yolo_loss_kernel(
    const float* __restrict__ pred,   // (B, 125, 26, 26)
    const float* __restrict__ tgt,    // (B, 26, 26, 25)
    float* __restrict__ out)          // 4 floats: box, conf, noobj, cls
{
    const float AW[NA] = {1.3221f, 3.19275f, 5.05587f, 9.47112f, 11.2364f};
    const float AH[NA] = {1.73145f, 4.00944f, 8.09892f, 4.84053f, 10.0071f};

    const int t = blockIdx.x * blockDim.x + threadIdx.x;   // grid == NCELLS exactly
    const int b  = t / NHW;
    const int hw = t - b * NHW;
    const float* p  = pred + (size_t)b * 125 * NHW + hw;   // channel stride NHW
    const float* tg = tgt + (size_t)t * 25;

    // ---- issue ALL box/conf/target loads up front, fully independent ----
    float v[NA][5];                  // [anchor][tc,tx,ty,tw,th]
    #pragma unroll
    for (int a = 0; a < NA; ++a) {
        #pragma unroll
        for (int c = 0; c < 5; ++c) {
            v[a][c] = p[(a * 25 + 20 + c) * NHW];
        }
    }
    float gconf = tg[20];
    float gx = tg[21], gy = tg[22], gw = tg[23], gh = tg[24];

    float g_x1 = gx - gw * 0.5f, g_x2 = gx + gw * 0.5f;
    float g_y1 = gy - gh * 0.5f, g_y2 = gy + gh * 0.5f;
    float g_area = gw * gh;

    float best_iou = -1.0f;
    int   best_a = 0;
    float bx = 0, by = 0, bw = 0, bh = 0, btc = 0;

    #pragma unroll
    for (int a = 0; a < NA; ++a) {
        float px = sigmoidf_(v[a][1]);
        float py = sigmoidf_(v[a][2]);
        float pw = __expf(v[a][3]) * AW[a];
        float ph = __expf(v[a][4]) * AH[a];
        float iw = fminf(px + pw * 0.5f, g_x2) - fmaxf(px - pw * 0.5f, g_x1);
        float ih = fminf(py + ph * 0.5f, g_y2) - fmaxf(py - ph * 0.5f, g_y1);
        iw = fmaxf(iw, 0.0f);
        ih = fmaxf(ih, 0.0f);
        float inter = iw * ih;
        float uni = pw * ph + g_area - inter;
        float iou = inter / (uni + 1e-10f);
        if (iou > best_iou) {   // strict >: first max wins ties (matches jnp.argmax)
            best_iou = iou;
            best_a = a;
            bx = px; by = py; bw = pw; bh = ph;
            btc = v[a][0];
        }
    }
    float bconf = sigmoidf_(btc);

    float box_l = 0.0f, conf_l = 0.0f, noobj_l = 0.0f, cls_l = 0.0f;

    if (gconf != 0.0f) {
        float dx = bx - gx, dy = by - gy, dw = bw - gw, dh = bh - gh;
        box_l = dx * dx + dy * dy + dw * dw + dh * dh;
        float dc = bconf - gconf;
        conf_l = dc * dc;

        // ---- class NLL, single pass: 20 logits + 20 one-hot, all independent ----
        const float* pc = p + best_a * 25 * NHW;
        float lg[NC], oh[NC];
        #pragma unroll
        for (int k = 0; k < NC; ++k) lg[k] = pc[k * NHW];
        #pragma unroll
        for (int k = 0; k < NC; ++k) oh[k] = tg[k];

        float m = lg[0];
        #pragma unroll
        for (int k = 1; k < NC; ++k) m = fmaxf(m, lg[k]);
        float s = 0.0f, l_sel = 0.0f;
        #pragma unroll
        for (int k = 0; k < NC; ++k) {
            s += __expf(lg[k] - m);
            if (oh[k] > 0.5f) l_sel = lg[k];
        }
        cls_l = -(l_sel - m - __logf(s));
    } else {
        noobj_l = bconf * bconf;
    }

    // ---- wave (64-lane) reduction ----
    #pragma unroll
    for (int off = 32; off > 0; off >>= 1) {
        box_l   += __shfl_down(box_l,   off, 64);
        conf_l  += __shfl_down(conf_l,  off, 64);
        noobj_l += __shfl_down(noobj_l, off, 64);
        cls_l   += __shfl_down(cls_l,   off, 64);
    }

    __shared__ float sred[4][4];   // 4 waves x 4 partials
    int wave = threadIdx.x >> 6;
    int lane = threadIdx.x & 63;
    if (lane == 0) {
        sred[wave][0] = box_l;
        sred[wave][1] = conf_l;
        sred[wave][2] = noobj_l;
        sred[wave][3] = cls_l;
    }
    __syncthreads();
    if (threadIdx.x == 0) {
        float b0 = 0, b1 = 0, b2 = 0, b3 = 0;
        #pragma unroll
        for (int w = 0; w < 4; ++w) {
            b0 += sred[w][0];
            b1 += sred[w][1];
            b2 += sred[w][2];
            b3 += sred[w][3];
        }
        atomicAdd(&out[0], b0 * (5.0f / 256.0f));
        atomicAdd(&out[1], b1 * (1.0f / 256.0f));
        atomicAdd(&out[2], b2 * (0.5f / 256.0f));
        atomicAdd(&out[3], b3 * (1.0f / 256.0f));
    }
}

extern "C" void kernel_launch(void* const* d_in, const int* in_sizes, int n_in,
                              void* d_out, int out_size, void* d_ws, size_t ws_size,
                              hipStream_t stream) {
    const float* pred = (const float*)d_in[0];
    const float* tgt  = (const float*)d_in[1];
    float* out = (float*)d_out;

    hipMemsetAsync(out, 0, out_size * sizeof(float), stream);

    dim3 grid(NCELLS / 256);
    dim3 block(256);
    hipLaunchKernelGGL(yolo_loss_kernel, grid, block, 0, stream,
                       pred, tgt, out);
}